// Round 4
// baseline (143.391 us; speedup 1.0000x reference)
//
#include <hip/hip_runtime.h>
#include <math.h>

typedef float f4 __attribute__((ext_vector_type(4)));

// ---------------------------------------------------------------------------
// Single fused kernel. Every WAVE redundantly computes the 16 spline params
// into registers (identical across lanes) -- no LDS, no __syncthreads, so the
// 8-deep float4 prefetch issued first keeps HBM busy during the ~1k-cycle
// setup. Eval uses the truncated-power identity:
//   f(xq) = P0(xq) + sum_j e_j * max(0, xq-k_j)^3
// with P0 = interval-0 cubic (expanded at 0), e_j = jump of the x^3 coeff.
// ---------------------------------------------------------------------------
__device__ __forceinline__ float eval_one(float xv,
                                          float c0, float c1, float c2, float c3,
                                          float k1, float k2, float k3,
                                          float k4, float k5, float k6,
                                          float e1, float e2, float e3,
                                          float e4, float e5, float e6)
{
    const float xq = fminf(fmaxf(xv * 0.57735026918962576f, 0.0f), 0.9999f);
    float acc = fmaf(fmaf(fmaf(c3, xq, c2), xq, c1), xq, c0);
    float r;
    r = fmaxf(xq - k1, 0.f); acc = fmaf(e1 * r, r * r, acc);
    r = fmaxf(xq - k2, 0.f); acc = fmaf(e2 * r, r * r, acc);
    r = fmaxf(xq - k3, 0.f); acc = fmaf(e3 * r, r * r, acc);
    r = fmaxf(xq - k4, 0.f); acc = fmaf(e4 * r, r * r, acc);
    r = fmaxf(xq - k5, 0.f); acc = fmaf(e5 * r, r * r, acc);
    r = fmaxf(xq - k6, 0.f); acc = fmaf(e6 * r, r * r, acc);
    return acc;
}

__global__ __launch_bounds__(256) void nsf_fused_kernel(
    const float* __restrict__ x,
    const float* __restrict__ a,
    const float* __restrict__ W1, const float* __restrict__ b1,
    const float* __restrict__ W2, const float* __restrict__ b2,
    const float* __restrict__ Ww, const float* __restrict__ bw,
    const float* __restrict__ Wk, const float* __restrict__ bk,
    float* __restrict__ out, int n)
{
    const int n4 = n >> 2;
    const int gid = blockIdx.x * blockDim.x + threadIdx.x;
    const int stride = gridDim.x * blockDim.x;
    const f4* __restrict__ x4 = reinterpret_cast<const f4*>(x);
    f4* __restrict__ o4 = reinterpret_cast<f4*>(out);

    // ---- prefetch: issue all 8 loads before the params compute ----------
    f4 v[8];
#pragma unroll
    for (int it = 0; it < 8; ++it) {
        const int idx = gid + it * stride;
        if (idx < n4) v[it] = __builtin_nontemporal_load(x4 + idx);
    }

    // ---- per-wave params compute (all lanes end with identical values) ---
    const int lane = threadIdx.x & 63;
    const int j16 = lane & 15;

    // layer 1+2: lanes 0..15's outputs (replicated x4 across the wave)
    const float n1own = __sinf(a[0] * W1[j16] + b1[j16]);
    float s2 = b2[j16];
#pragma unroll
    for (int i = 0; i < 16; ++i)
        s2 = fmaf(__shfl(n1own, i, 64), W2[i * 16 + j16], s2);
    const float n2own = __sinf(s2);

    float n2[16];
#pragma unroll
    for (int i = 0; i < 16; ++i) n2[i] = __shfl(n2own, i, 64);

    // heads: fully redundant per lane; weight addresses wave-uniform -> s_load
    float w[9];
#pragma unroll
    for (int j = 0; j < 9; ++j) {
        float s = bw[j];
#pragma unroll
        for (int i = 0; i < 16; ++i) s = fmaf(n2[i], Ww[i * 9 + j], s);
        w[j] = s;
    }
    float kr[7];
#pragma unroll
    for (int j = 0; j < 7; ++j) {
        float s = bk[j];
#pragma unroll
        for (int i = 0; i < 16; ++i) s = fmaf(n2[i], Wk[i * 7 + j], s);
        kr[j] = s;
    }

    // softmax + cumsum -> strictly increasing interior knots in (0,1]
    float m = kr[0];
#pragma unroll
    for (int j = 1; j < 7; ++j) m = fmaxf(m, kr[j]);
    float ee[7], se = 0.f;
#pragma unroll
    for (int j = 0; j < 7; ++j) { ee[j] = __expf(kr[j] - m); se += ee[j]; }
    const float sinv = __builtin_amdgcn_rcpf(se);

    // padded knots t[14] = [0,0,0, 0, kk1..kk6, kk7, 1,1,1]; all const-indexed
    float t[14], cc[10];
    t[0] = t[1] = t[2] = t[3] = 0.f;
    {
        float cum = 0.f;
#pragma unroll
        for (int j = 0; j < 7; ++j) { cum += ee[j] * sinv; t[4 + j] = cum; }
    }
    t[11] = t[12] = t[13] = 1.f;
    cc[0] = 0.f;
#pragma unroll
    for (int j = 0; j < 9; ++j) cc[1 + j] = w[j];

    // symbolic de Boor per interval, fully unrolled (compile-time indices).
    // d[j] are cubics in u = xq - t[k]; alpha = A + B*u, denominators > 0.
    float p0c0 = 0.f, p0c1 = 0.f, p0c2 = 0.f, p0c3 = 0.f;
    float d3v[7];
#pragma unroll
    for (int iv = 0; iv < 7; ++iv) {
        const int k = 3 + iv;
        const float tk = t[k];
        float d[4][4];
#pragma unroll
        for (int j = 0; j < 4; ++j) {
            d[j][0] = cc[k - 3 + j];
            d[j][1] = d[j][2] = d[j][3] = 0.f;
        }
#pragma unroll
        for (int r = 1; r <= 3; ++r) {
#pragma unroll
            for (int jj = 0; jj < 3; ++jj) {
                const int j = 3 - jj;
                if (j < r) continue;
                const float tlo = t[k + j - 3];
                const float thi = t[k + j + 1 - r];
                const float B = __builtin_amdgcn_rcpf(thi - tlo);
                const float A = (tk - tlo) * B;
                float nd[4];
#pragma unroll
                for (int nn = 0; nn < 4; ++nn) nd[nn] = d[j - 1][nn];
#pragma unroll
                for (int nn = 0; nn < 3; ++nn) {
                    if (nn < r) {
                        const float en = d[j][nn] - d[j - 1][nn];
                        nd[nn]     += A * en;
                        nd[nn + 1] += B * en;
                    }
                }
#pragma unroll
                for (int nn = 0; nn < 4; ++nn) d[j][nn] = nd[nn];
            }
        }
        d3v[iv] = d[3][3];
        if (iv == 0) { p0c0 = d[3][0]; p0c1 = d[3][1]; p0c2 = d[3][2]; p0c3 = d[3][3]; }
    }

    const float k1 = t[4], k2 = t[5], k3 = t[6], k4 = t[7], k5 = t[8], k6 = t[9];
    const float e1 = d3v[1] - d3v[0], e2 = d3v[2] - d3v[1], e3 = d3v[3] - d3v[2];
    const float e4 = d3v[4] - d3v[3], e5 = d3v[5] - d3v[4], e6 = d3v[6] - d3v[5];

    // ---- eval + store (no barrier was ever needed) -----------------------
#pragma unroll
    for (int it = 0; it < 8; ++it) {
        const int idx = gid + it * stride;
        if (idx < n4) {
            f4 r;
            r.x = eval_one(v[it].x, p0c0,p0c1,p0c2,p0c3, k1,k2,k3,k4,k5,k6, e1,e2,e3,e4,e5,e6);
            r.y = eval_one(v[it].y, p0c0,p0c1,p0c2,p0c3, k1,k2,k3,k4,k5,k6, e1,e2,e3,e4,e5,e6);
            r.z = eval_one(v[it].z, p0c0,p0c1,p0c2,p0c3, k1,k2,k3,k4,k5,k6, e1,e2,e3,e4,e5,e6);
            r.w = eval_one(v[it].w, p0c0,p0c1,p0c2,p0c3, k1,k2,k3,k4,k5,k6, e1,e2,e3,e4,e5,e6);
            __builtin_nontemporal_store(r, o4 + idx);
        }
    }
    // generic overflow guard (empty at n = 256^3 with the launch config below)
    for (int idx = gid + 8 * stride; idx < n4; idx += stride) {
        const f4 vv = x4[idx];
        f4 r;
        r.x = eval_one(vv.x, p0c0,p0c1,p0c2,p0c3, k1,k2,k3,k4,k5,k6, e1,e2,e3,e4,e5,e6);
        r.y = eval_one(vv.y, p0c0,p0c1,p0c2,p0c3, k1,k2,k3,k4,k5,k6, e1,e2,e3,e4,e5,e6);
        r.z = eval_one(vv.z, p0c0,p0c1,p0c2,p0c3, k1,k2,k3,k4,k5,k6, e1,e2,e3,e4,e5,e6);
        r.w = eval_one(vv.w, p0c0,p0c1,p0c2,p0c3, k1,k2,k3,k4,k5,k6, e1,e2,e3,e4,e5,e6);
        o4[idx] = r;
    }
    // scalar tail (n % 4 != 0 safety; empty here)
    for (int j = (n4 << 2) + gid; j < n; j += stride)
        out[j] = eval_one(x[j], p0c0,p0c1,p0c2,p0c3, k1,k2,k3,k4,k5,k6, e1,e2,e3,e4,e5,e6);
}

extern "C" void kernel_launch(void* const* d_in, const int* in_sizes, int n_in,
                              void* d_out, int out_size, void* d_ws, size_t ws_size,
                              hipStream_t stream)
{
    const float* x  = (const float*)d_in[0];
    const float* a  = (const float*)d_in[1];
    const float* W1 = (const float*)d_in[2];
    const float* b1 = (const float*)d_in[3];
    const float* W2 = (const float*)d_in[4];
    const float* b2 = (const float*)d_in[5];
    const float* Ww = (const float*)d_in[6];
    const float* bw = (const float*)d_in[7];
    const float* Wk = (const float*)d_in[8];
    const float* bk = (const float*)d_in[9];
    float* out = (float*)d_out;
    const int n = out_size;

    // 8 float4s per thread: n=256^3 -> exactly 2048 blocks x 256 threads.
    const int n4 = n >> 2;
    int blocks = (n4 + 256 * 8 - 1) / (256 * 8);
    if (blocks < 1) blocks = 1;

    hipLaunchKernelGGL(nsf_fused_kernel, dim3(blocks), dim3(256), 0, stream,
                       x, a, W1, b1, W2, b2, Ww, bw, Wk, bk, out, n);
}

// Round 5
// 141.167 us; speedup vs baseline: 1.0158x; 1.0158x over previous
//
#include <hip/hip_runtime.h>
#include <math.h>

typedef float f4 __attribute__((ext_vector_type(4)));

// ---------------------------------------------------------------------------
// Single fused kernel, cheap per-wave params (R4 post-mortem fix).
//
// Every wave redundantly computes 15 wave-uniform spline params in registers:
//   P0 cubic (c0=0, c1, c2, c3), interior knots k1..k6, jumps e1..e6
// via the truncated-power identity
//   f(xq) = P0(xq) + sum_j e_j * max(0, xq - k_j)^3.
// Params are derived with B-spline DIFFERENCING (3 passes), not symbolic
// de Boor: ~100 insts instead of ~560, peak live set ~85 floats -> no scratch
// spill (R4's regression). Heads are lane-split (16 lanes x 16 fma) instead
// of 256 redundant fma. No LDS, no __syncthreads.
// ---------------------------------------------------------------------------
__device__ __forceinline__ float eval_one(float xv,
                                          float c1, float c2, float c3,
                                          float k1, float k2, float k3,
                                          float k4, float k5, float k6,
                                          float e1, float e2, float e3,
                                          float e4, float e5, float e6)
{
    const float xq = fminf(fmaxf(xv * 0.57735026918962576f, 0.0f), 0.9999f);
    float acc = xq * fmaf(fmaf(c3, xq, c2), xq, c1);   // P0 (c0 = 0 exactly)
    float r;
    r = fmaxf(xq - k1, 0.f); acc = fmaf(e1 * r, r * r, acc);
    r = fmaxf(xq - k2, 0.f); acc = fmaf(e2 * r, r * r, acc);
    r = fmaxf(xq - k3, 0.f); acc = fmaf(e3 * r, r * r, acc);
    r = fmaxf(xq - k4, 0.f); acc = fmaf(e4 * r, r * r, acc);
    r = fmaxf(xq - k5, 0.f); acc = fmaf(e5 * r, r * r, acc);
    r = fmaxf(xq - k6, 0.f); acc = fmaf(e6 * r, r * r, acc);
    return acc;
}

__global__ __launch_bounds__(256) void nsf_fused2_kernel(
    const float* __restrict__ x,
    const float* __restrict__ a,
    const float* __restrict__ W1, const float* __restrict__ b1,
    const float* __restrict__ W2, const float* __restrict__ b2,
    const float* __restrict__ Ww, const float* __restrict__ bw,
    const float* __restrict__ Wk, const float* __restrict__ bk,
    float* __restrict__ out, int n)
{
    const int n4 = n >> 2;
    const int gid = blockIdx.x * blockDim.x + threadIdx.x;
    const int stride = gridDim.x * blockDim.x;
    const f4* __restrict__ x4 = reinterpret_cast<const f4*>(x);
    f4* __restrict__ o4 = reinterpret_cast<f4*>(out);

    const int j16 = threadIdx.x & 15;

    // ---- issue all weight loads first (oldest in vmem queue) -------------
    const float av  = a[0];
    const float w1v = W1[j16];
    const float b1v = b1[j16];
    const float b2v = b2[j16];
    float w2l[16];
#pragma unroll
    for (int i = 0; i < 16; ++i) w2l[i] = W2[i * 16 + j16];
    const bool isw = (j16 < 9);
    const float* hW = isw ? (Ww + j16) : (Wk + (j16 - 9));
    const int hs = isw ? 9 : 7;
    const float hbv = isw ? bw[j16] : bk[j16 - 9];
    float hl[16];
#pragma unroll
    for (int i = 0; i < 16; ++i) hl[i] = hW[i * hs];

    // ---- prefetch x: 8 float4 per thread ---------------------------------
    f4 v[8];
#pragma unroll
    for (int it = 0; it < 8; ++it) {
        const int idx = gid + it * stride;
        if (idx < n4) v[it] = __builtin_nontemporal_load(x4 + idx);
    }

    // ---- MLP: lanes 0..15's results, replicated x4 across the wave -------
    const float n1own = __sinf(fmaf(av, w1v, b1v));
    float s2 = b2v;
#pragma unroll
    for (int i = 0; i < 16; ++i)
        s2 = fmaf(__shfl(n1own, i, 64), w2l[i], s2);
    const float n2own = __sinf(s2);

    // heads, lane-split: lane j -> w[j] (j<9) or kr[j-9]
    float hsum = hbv;
#pragma unroll
    for (int i = 0; i < 16; ++i)
        hsum = fmaf(__shfl(n2own, i, 64), hl[i], hsum);

    // broadcast all 16 head outputs to every lane
    float hv[16];
#pragma unroll
    for (int i = 0; i < 16; ++i) hv[i] = __shfl(hsum, i, 64);
    // hv[0..8] = w0..w8 (control points 1..9), hv[9..15] = kr[0..6]

    // ---- softmax + cumsum -> interior knots (strictly increasing) --------
    float m = hv[9];
#pragma unroll
    for (int j = 1; j < 7; ++j) m = fmaxf(m, hv[9 + j]);
    float ex[7], se = 0.f;
#pragma unroll
    for (int j = 0; j < 7; ++j) { ex[j] = __expf(hv[9 + j] - m); se += ex[j]; }
    const float sinv = __builtin_amdgcn_rcpf(se);

    // padded knots t[14] = [0,0,0,0, kk1..kk7, 1,1,1]  (all const-indexed)
    float t[14];
    t[0] = t[1] = t[2] = t[3] = 0.f;
    {
        float cum = 0.f;
#pragma unroll
        for (int j = 0; j < 7; ++j) { cum += ex[j] * sinv; t[4 + j] = cum; }
    }
    t[11] = t[12] = t[13] = 1.f;

    // control points cc[0..9] = [0, hv[0..8]]
    float cc[10];
    cc[0] = 0.f;
#pragma unroll
    for (int j = 0; j < 9; ++j) cc[1 + j] = hv[j];

    // ---- three differencing passes: f''' piecewise-constant coeffs -------
    // every denominator spans >= 1 interior knot gap -> strictly > 0
    float c1v[10];
#pragma unroll
    for (int i = 1; i < 10; ++i)
        c1v[i] = 3.f * (cc[i] - cc[i - 1]) * __builtin_amdgcn_rcpf(t[i + 3] - t[i]);
    float c2v[10];
#pragma unroll
    for (int i = 2; i < 10; ++i)
        c2v[i] = 2.f * (c1v[i] - c1v[i - 1]) * __builtin_amdgcn_rcpf(t[i + 2] - t[i]);
    float c3v[10];
#pragma unroll
    for (int i = 3; i < 10; ++i)
        c3v[i] = (c2v[i] - c2v[i - 1]) * __builtin_amdgcn_rcpf(t[i + 1] - t[i]);

    // P0 from left-endpoint derivatives (quadruple knot at 0: f(0)=cc[0]=0)
    const float p0c1 = c1v[1];            // f'(0)
    const float p0c2 = c2v[2] * 0.5f;     // f''(0)/2
    const float p0c3 = c3v[3] * (1.f / 6.f);

    const float k1 = t[4], k2 = t[5], k3 = t[6], k4 = t[7], k5 = t[8], k6 = t[9];
    const float e1 = (c3v[4] - c3v[3]) * (1.f / 6.f);
    const float e2 = (c3v[5] - c3v[4]) * (1.f / 6.f);
    const float e3 = (c3v[6] - c3v[5]) * (1.f / 6.f);
    const float e4 = (c3v[7] - c3v[6]) * (1.f / 6.f);
    const float e5 = (c3v[8] - c3v[7]) * (1.f / 6.f);
    const float e6 = (c3v[9] - c3v[8]) * (1.f / 6.f);

    // ---- eval + store ----------------------------------------------------
#pragma unroll
    for (int it = 0; it < 8; ++it) {
        const int idx = gid + it * stride;
        if (idx < n4) {
            f4 r;
            r.x = eval_one(v[it].x, p0c1,p0c2,p0c3, k1,k2,k3,k4,k5,k6, e1,e2,e3,e4,e5,e6);
            r.y = eval_one(v[it].y, p0c1,p0c2,p0c3, k1,k2,k3,k4,k5,k6, e1,e2,e3,e4,e5,e6);
            r.z = eval_one(v[it].z, p0c1,p0c2,p0c3, k1,k2,k3,k4,k5,k6, e1,e2,e3,e4,e5,e6);
            r.w = eval_one(v[it].w, p0c1,p0c2,p0c3, k1,k2,k3,k4,k5,k6, e1,e2,e3,e4,e5,e6);
            __builtin_nontemporal_store(r, o4 + idx);
        }
    }
    // generic overflow guard (empty at n = 256^3 with this launch config)
    for (int idx = gid + 8 * stride; idx < n4; idx += stride) {
        const f4 vv = x4[idx];
        f4 r;
        r.x = eval_one(vv.x, p0c1,p0c2,p0c3, k1,k2,k3,k4,k5,k6, e1,e2,e3,e4,e5,e6);
        r.y = eval_one(vv.y, p0c1,p0c2,p0c3, k1,k2,k3,k4,k5,k6, e1,e2,e3,e4,e5,e6);
        r.z = eval_one(vv.z, p0c1,p0c2,p0c3, k1,k2,k3,k4,k5,k6, e1,e2,e3,e4,e5,e6);
        r.w = eval_one(vv.w, p0c1,p0c2,p0c3, k1,k2,k3,k4,k5,k6, e1,e2,e3,e4,e5,e6);
        o4[idx] = r;
    }
    // scalar tail (n % 4 != 0 safety; empty here)
    for (int j = (n4 << 2) + gid; j < n; j += stride)
        out[j] = eval_one(x[j], p0c1,p0c2,p0c3, k1,k2,k3,k4,k5,k6, e1,e2,e3,e4,e5,e6);
}

extern "C" void kernel_launch(void* const* d_in, const int* in_sizes, int n_in,
                              void* d_out, int out_size, void* d_ws, size_t ws_size,
                              hipStream_t stream)
{
    const float* x  = (const float*)d_in[0];
    const float* a  = (const float*)d_in[1];
    const float* W1 = (const float*)d_in[2];
    const float* b1 = (const float*)d_in[3];
    const float* W2 = (const float*)d_in[4];
    const float* b2 = (const float*)d_in[5];
    const float* Ww = (const float*)d_in[6];
    const float* bw = (const float*)d_in[7];
    const float* Wk = (const float*)d_in[8];
    const float* bk = (const float*)d_in[9];
    float* out = (float*)d_out;
    const int n = out_size;

    // 8 float4s per thread: n=256^3 -> exactly 2048 blocks x 256 threads.
    const int n4 = n >> 2;
    int blocks = (n4 + 256 * 8 - 1) / (256 * 8);
    if (blocks < 1) blocks = 1;

    hipLaunchKernelGGL(nsf_fused2_kernel, dim3(blocks), dim3(256), 0, stream,
                       x, a, W1, b1, W2, b2, Ww, bw, Wk, bk, out, n);
}

// Round 6
// 128.392 us; speedup vs baseline: 1.1168x; 1.0995x over previous
//
#include <hip/hip_runtime.h>
#include <math.h>

typedef float f4 __attribute__((ext_vector_type(4)));

// ---------------------------------------------------------------------------
// Fused attempt 3 (R5 post-mortem: revert every delta vs the fast R3 eval).
//  - plain x loads (NT loads suspected of bypassing L2/L3 hits on the
//    freshly-restored input; R2's FETCH_SIZE=33MB of 67MB proved L3 serves
//    half the read when plain loads are used), NT stores only
//  - no prefetch arrays: same grid-stride load->eval->store loop as R3
//  - per-wave params via readlane broadcasts; all 15 final params forced
//    uniform with readfirstlane -> SGPRs, keeping the loop's VGPR count low
// Eval identity (verified R3/R5, absmax 6.1e-5):
//   f(xq) = xq*(c1 + xq*(c2 + xq*c3)) + sum_j e_j * max(0, xq-k_j)^3
// ---------------------------------------------------------------------------
__device__ __forceinline__ float rdlane(float v, int l) {
    return __int_as_float(__builtin_amdgcn_readlane(__float_as_int(v), l));
}
__device__ __forceinline__ float rdfirst(float v) {
    return __int_as_float(__builtin_amdgcn_readfirstlane(__float_as_int(v)));
}

__device__ __forceinline__ float eval_one(float xv,
                                          float c1, float c2, float c3,
                                          float k1, float k2, float k3,
                                          float k4, float k5, float k6,
                                          float e1, float e2, float e3,
                                          float e4, float e5, float e6)
{
    const float xq = fminf(fmaxf(xv * 0.57735026918962576f, 0.0f), 0.9999f);
    float acc = xq * fmaf(fmaf(c3, xq, c2), xq, c1);   // P0 (c0 = 0 exactly)
    float r;
    r = fmaxf(xq - k1, 0.f); acc = fmaf(e1 * r, r * r, acc);
    r = fmaxf(xq - k2, 0.f); acc = fmaf(e2 * r, r * r, acc);
    r = fmaxf(xq - k3, 0.f); acc = fmaf(e3 * r, r * r, acc);
    r = fmaxf(xq - k4, 0.f); acc = fmaf(e4 * r, r * r, acc);
    r = fmaxf(xq - k5, 0.f); acc = fmaf(e5 * r, r * r, acc);
    r = fmaxf(xq - k6, 0.f); acc = fmaf(e6 * r, r * r, acc);
    return acc;
}

__global__ __launch_bounds__(256) void nsf_fused3_kernel(
    const float* __restrict__ x,
    const float* __restrict__ a,
    const float* __restrict__ W1, const float* __restrict__ b1,
    const float* __restrict__ W2, const float* __restrict__ b2,
    const float* __restrict__ Ww, const float* __restrict__ bw,
    const float* __restrict__ Wk, const float* __restrict__ bk,
    float* __restrict__ out, int n)
{
    // ---- per-wave params (result identical on every lane, lands in SGPRs) -
    const int j16 = threadIdx.x & 15;

    const float n1own = __sinf(fmaf(a[0], W1[j16], b1[j16]));
    float s2 = b2[j16];
#pragma unroll
    for (int i = 0; i < 16; ++i)
        s2 = fmaf(rdlane(n1own, i), W2[i * 16 + j16], s2);
    const float n2own = __sinf(s2);

    // heads lane-split: lane j<9 -> w[j]; lanes 9..15 -> kr[j-9]
    const bool isw = (j16 < 9);
    const float* hp = isw ? (Ww + j16) : (Wk + (j16 - 9));
    const int hs = isw ? 9 : 7;
    float hsum = isw ? bw[j16] : bk[j16 - 9];
#pragma unroll
    for (int i = 0; i < 16; ++i)
        hsum = fmaf(rdlane(n2own, i), hp[i * hs], hsum);

    // broadcast the 16 head outputs -> uniform (SGPR-backed)
    float hv[16];
#pragma unroll
    for (int i = 0; i < 16; ++i) hv[i] = rdlane(hsum, i);
    // hv[0..8] = w0..w8 (control points 1..9), hv[9..15] = kr[0..6]

    // softmax + cumsum -> strictly increasing interior knots in (0,1]
    float m = hv[9];
#pragma unroll
    for (int j = 1; j < 7; ++j) m = fmaxf(m, hv[9 + j]);
    float ex[7], se = 0.f;
#pragma unroll
    for (int j = 0; j < 7; ++j) { ex[j] = __expf(hv[9 + j] - m); se += ex[j]; }
    const float sinv = __builtin_amdgcn_rcpf(se);

    // padded knots t[14] = [0,0,0,0, kk1..kk7, 1,1,1]; all const-indexed
    float t[14];
    t[0] = t[1] = t[2] = t[3] = 0.f;
    {
        float cum = 0.f;
#pragma unroll
        for (int j = 0; j < 7; ++j) { cum += ex[j] * sinv; t[4 + j] = cum; }
    }
    t[11] = t[12] = t[13] = 1.f;

    // control points cc[0..9] = [0, hv[0..8]]
    float cc[10];
    cc[0] = 0.f;
#pragma unroll
    for (int j = 0; j < 9; ++j) cc[1 + j] = hv[j];

    // three differencing passes -> piecewise-constant f''' coefficients
    // (every denominator spans >= 1 interior knot gap -> strictly > 0)
    float c1v[10];
#pragma unroll
    for (int i = 1; i < 10; ++i)
        c1v[i] = 3.f * (cc[i] - cc[i - 1]) * __builtin_amdgcn_rcpf(t[i + 3] - t[i]);
    float c2v[10];
#pragma unroll
    for (int i = 2; i < 10; ++i)
        c2v[i] = 2.f * (c1v[i] - c1v[i - 1]) * __builtin_amdgcn_rcpf(t[i + 2] - t[i]);
    float c3v[10];
#pragma unroll
    for (int i = 3; i < 10; ++i)
        c3v[i] = (c2v[i] - c2v[i - 1]) * __builtin_amdgcn_rcpf(t[i + 1] - t[i]);

    // final 15 params, explicitly uniform -> SGPRs for the stream loop
    const float p0c1 = rdfirst(c1v[1]);                 // f'(0)
    const float p0c2 = rdfirst(c2v[2] * 0.5f);          // f''(0)/2
    const float p0c3 = rdfirst(c3v[3] * (1.f / 6.f));   // f'''(0+)/6
    const float k1 = rdfirst(t[4]), k2 = rdfirst(t[5]), k3 = rdfirst(t[6]);
    const float k4 = rdfirst(t[7]), k5 = rdfirst(t[8]), k6 = rdfirst(t[9]);
    const float e1 = rdfirst((c3v[4] - c3v[3]) * (1.f / 6.f));
    const float e2 = rdfirst((c3v[5] - c3v[4]) * (1.f / 6.f));
    const float e3 = rdfirst((c3v[6] - c3v[5]) * (1.f / 6.f));
    const float e4 = rdfirst((c3v[7] - c3v[6]) * (1.f / 6.f));
    const float e5 = rdfirst((c3v[8] - c3v[7]) * (1.f / 6.f));
    const float e6 = rdfirst((c3v[9] - c3v[8]) * (1.f / 6.f));

    // ---- stream: identical structure to R3's eval kernel ------------------
    const int n4 = n >> 2;
    const int gid = blockIdx.x * blockDim.x + threadIdx.x;
    const int stride = gridDim.x * blockDim.x;
    const f4* __restrict__ x4 = reinterpret_cast<const f4*>(x);
    f4* __restrict__ o4 = reinterpret_cast<f4*>(out);

    for (int idx = gid; idx < n4; idx += stride) {
        const f4 v = x4[idx];
        f4 r;
        r.x = eval_one(v.x, p0c1,p0c2,p0c3, k1,k2,k3,k4,k5,k6, e1,e2,e3,e4,e5,e6);
        r.y = eval_one(v.y, p0c1,p0c2,p0c3, k1,k2,k3,k4,k5,k6, e1,e2,e3,e4,e5,e6);
        r.z = eval_one(v.z, p0c1,p0c2,p0c3, k1,k2,k3,k4,k5,k6, e1,e2,e3,e4,e5,e6);
        r.w = eval_one(v.w, p0c1,p0c2,p0c3, k1,k2,k3,k4,k5,k6, e1,e2,e3,e4,e5,e6);
        __builtin_nontemporal_store(r, o4 + idx);
    }
    // scalar tail (n % 4 != 0 safety; empty at n = 256^3)
    for (int j = (n4 << 2) + gid; j < n; j += stride)
        out[j] = eval_one(x[j], p0c1,p0c2,p0c3, k1,k2,k3,k4,k5,k6, e1,e2,e3,e4,e5,e6);
}

extern "C" void kernel_launch(void* const* d_in, const int* in_sizes, int n_in,
                              void* d_out, int out_size, void* d_ws, size_t ws_size,
                              hipStream_t stream)
{
    const float* x  = (const float*)d_in[0];
    const float* a  = (const float*)d_in[1];
    const float* W1 = (const float*)d_in[2];
    const float* b1 = (const float*)d_in[3];
    const float* W2 = (const float*)d_in[4];
    const float* b2 = (const float*)d_in[5];
    const float* Ww = (const float*)d_in[6];
    const float* bw = (const float*)d_in[7];
    const float* Wk = (const float*)d_in[8];
    const float* bk = (const float*)d_in[9];
    float* out = (float*)d_out;
    const int n = out_size;

    // 8 float4s per thread grid-stride: n=256^3 -> 2048 blocks x 256 threads.
    const int n4 = n >> 2;
    int blocks = (n4 + 256 * 8 - 1) / (256 * 8);
    if (blocks < 1) blocks = 1;

    hipLaunchKernelGGL(nsf_fused3_kernel, dim3(blocks), dim3(256), 0, stream,
                       x, a, W1, b1, W2, b2, Ww, bw, Wk, bk, out, n);
}